// Round 8
// baseline (45.342 us; speedup 1.0000x reference)
//
#include <hip/hip_runtime.h>

// Fused: 2x2x2 max-pool (stride 2) + per-channel bias + logsumexp over C=64 + ReLU.
// x = const float* [4,64,64,64,64] (harness upcasts fp16->f32), bias = const float* [64],
// out = float* [4,1,32,32,32].
//
// Ladder: R4 float2/16w-CU = 43.4us; R5 float4 = 45.4 (VGPR/TLP regression);
// R6 float2/32w-CU = 43.4 -> occupancy not the limiter; plateau 6.2 TB/s.
// R7: nontemporal loads on x (read-once 268MB > 256MB L3; skip LLC allocation).
// R8: fix R7 compile error — __builtin_nontemporal_load needs a NATIVE vector
// type, not HIP_vector_type; use ext_vector_type(2) float.

typedef float vf2 __attribute__((ext_vector_type(2)));

__global__ __launch_bounds__(256) void fused_pool_lse_relu(
    const float* __restrict__ x, const float* __restrict__ bias,
    float* __restrict__ out)
{
    __shared__ float s_bias[64];
    if (threadIdx.x < 64) s_bias[threadIdx.x] = bias[threadIdx.x];
    __syncthreads();

    const int lane = threadIdx.x & 63;
    const int wave = threadIdx.x >> 6;
    const int q    = lane >> 4;          // channel quarter: c = 16q .. 16q+15
    const int t    = lane & 15;          // w' offset within the wave's 16-chunk

    const int o = blockIdx.x * 64 + wave * 16 + t;   // output voxel id

    const int wp = o & 31;          // output w'
    const int hp = (o >> 5) & 31;   // output h'
    const int dp = (o >> 10) & 31;  // output d'
    const int n  = o >> 15;         // batch

    // element strides (f32): w:1, h:64, d:4096, c:262144, n:64*262144
    const size_t CS = 262144;
    const float* base = x
        + (size_t)n * (64 * CS)
        + (size_t)(q * 16) * CS
        + (size_t)dp * 8192        // 2*dp*4096
        + (size_t)hp * 128         // 2*hp*64
        + (size_t)wp * 2;

    float vals[16];
#pragma unroll
    for (int cc = 0; cc < 16; ++cc) {
        const vf2* p = (const vf2*)(base + (size_t)cc * CS);
        const vf2 a = __builtin_nontemporal_load(p);           // d0,h0 (w0,w1)
        const vf2 b = __builtin_nontemporal_load(p + 32);      // d0,h1  (+64 floats)
        const vf2 c = __builtin_nontemporal_load(p + 2048);    // d1,h0  (+4096 floats)
        const vf2 d = __builtin_nontemporal_load(p + 2080);    // d1,h1  (+4160 floats)
        vals[cc] = fmaxf(fmaxf(fmaxf(a.x, a.y), fmaxf(b.x, b.y)),
                         fmaxf(fmaxf(c.x, c.y), fmaxf(d.x, d.y)))
                 + s_bias[q * 16 + cc];
    }

    // two-pass logsumexp over this lane's 16 channels (static indices)
    float m = vals[0];
#pragma unroll
    for (int cc = 1; cc < 16; ++cc) m = fmaxf(m, vals[cc]);
    float s = 0.0f;
#pragma unroll
    for (int cc = 0; cc < 16; ++cc) s += __expf(vals[cc] - m);

    // merge the 4 channel quarters across the lane quad
    {
        const float mo = __shfl_xor(m, 16), so = __shfl_xor(s, 16);
        const float M = fmaxf(m, mo);
        s = s * __expf(m - M) + so * __expf(mo - M);
        m = M;
    }
    {
        const float mo = __shfl_xor(m, 32), so = __shfl_xor(s, 32);
        const float M = fmaxf(m, mo);
        s = s * __expf(m - M) + so * __expf(mo - M);
        m = M;
    }

    if (q == 0) out[o] = fmaxf(m + __logf(s), 0.0f);   // ReLU
}

extern "C" void kernel_launch(void* const* d_in, const int* in_sizes, int n_in,
                              void* d_out, int out_size, void* d_ws, size_t ws_size,
                              hipStream_t stream)
{
    const float* x    = (const float*)d_in[0];
    const float* bias = (const float*)d_in[1];
    float* out = (float*)d_out;

    // 131072 outputs, 64 per block (4 waves x 16) -> 2048 blocks
    const int blocks = out_size / 64;
    fused_pool_lse_relu<<<blocks, 256, 0, stream>>>(x, bias, out);
}

// Round 9
// 45.263 us; speedup vs baseline: 1.0017x; 1.0017x over previous
//
#include <hip/hip_runtime.h>

// Fused: 2x2x2 max-pool (stride 2) + per-channel bias + logsumexp over C=64 + ReLU.
// x = const float* [4,64,64,64,64] (harness upcasts fp16->f32), bias = const float* [64],
// out = float* [4,1,32,32,32].
//
// Ladder: R4 float2/16w-CU 43.4us | R5 float4/2w-SIMD 45.4 (VGPR->TLP collapse)
//         R6 float2/32w-CU 43.4 (occupancy not limiter) | R8 nontemporal 45.3
//         (nt forfeits cross-replay L3 hits -> REGRESSION; keep default caching).
// R9 (final probe): float4 WITH high TLP — quad channel split (16 ch/lane,
// v0[16]+v1[16] ~ 110 VGPR -> ~4 waves/SIMD), 2 outputs/lane. If this doesn't
// beat 43.4, width is exonerated and 6.2 TB/s is the genuine read ceiling.

__global__ __launch_bounds__(256) void fused_pool_lse_relu(
    const float* __restrict__ x, const float* __restrict__ bias,
    float* __restrict__ out)
{
    __shared__ float s_bias[64];
    if (threadIdx.x < 64) s_bias[threadIdx.x] = bias[threadIdx.x];
    __syncthreads();

    const int lane = threadIdx.x & 63;
    const int wave = threadIdx.x >> 6;
    const int q    = lane >> 4;          // channel quarter: c = 16q .. 16q+15
    const int t    = lane & 15;          // w'-pair index (w' = 2t, 2t+1)

    // wave = one (n, d', h') row of 32 outputs
    const int r  = blockIdx.x * 4 + wave;     // row id in [0, 4096)
    const int n  = r >> 10;
    const int dp = (r >> 5) & 31;
    const int hp = r & 31;

    // element strides (f32): w:1, h:64, d:4096, c:262144, n:64*262144
    const size_t CS = 262144;
    const float* base = x
        + (size_t)n * (64 * CS)
        + (size_t)(q * 16) * CS
        + (size_t)dp * 8192        // 2*dp*4096
        + (size_t)hp * 128         // 2*hp*64
        + (size_t)t * 4;           // input w = 4t .. 4t+3

    float v0[16], v1[16];
#pragma unroll
    for (int cc = 0; cc < 16; ++cc) {
        const float* p = base + (size_t)cc * CS;
        const float4 a = *(const float4*)(p);          // d0,h0
        const float4 b = *(const float4*)(p + 64);     // d0,h1
        const float4 c = *(const float4*)(p + 4096);   // d1,h0
        const float4 d = *(const float4*)(p + 4160);   // d1,h1
        const float bia = s_bias[q * 16 + cc];
        v0[cc] = fmaxf(fmaxf(fmaxf(a.x, a.y), fmaxf(b.x, b.y)),
                       fmaxf(fmaxf(c.x, c.y), fmaxf(d.x, d.y))) + bia;
        v1[cc] = fmaxf(fmaxf(fmaxf(a.z, a.w), fmaxf(b.z, b.w)),
                       fmaxf(fmaxf(c.z, c.w), fmaxf(d.z, d.w))) + bia;
    }

    // two-pass logsumexp per output over this lane's 16 channels
    float m0 = v0[0], m1 = v1[0];
#pragma unroll
    for (int cc = 1; cc < 16; ++cc) { m0 = fmaxf(m0, v0[cc]); m1 = fmaxf(m1, v1[cc]); }
    float s0 = 0.0f, s1 = 0.0f;
#pragma unroll
    for (int cc = 0; cc < 16; ++cc) { s0 += __expf(v0[cc] - m0); s1 += __expf(v1[cc] - m1); }

    // merge the 4 channel quarters across the lane quad (xor 16, then 32)
#pragma unroll
    for (int d = 16; d <= 32; d <<= 1) {
        const float m0o = __shfl_xor(m0, d), s0o = __shfl_xor(s0, d);
        const float m1o = __shfl_xor(m1, d), s1o = __shfl_xor(s1, d);
        const float M0 = fmaxf(m0, m0o), M1 = fmaxf(m1, m1o);
        s0 = s0 * __expf(m0 - M0) + s0o * __expf(m0o - M0);
        s1 = s1 * __expf(m1 - M1) + s1o * __expf(m1o - M1);
        m0 = M0; m1 = M1;
    }

    if (q == 0) {
        float2 rr; 
        rr.x = fmaxf(m0 + __logf(s0), 0.0f);
        rr.y = fmaxf(m1 + __logf(s1), 0.0f);
        *(float2*)(out + r * 32 + t * 2) = rr;
    }
}

extern "C" void kernel_launch(void* const* d_in, const int* in_sizes, int n_in,
                              void* d_out, int out_size, void* d_ws, size_t ws_size,
                              hipStream_t stream)
{
    const float* x    = (const float*)d_in[0];
    const float* bias = (const float*)d_in[1];
    float* out = (float*)d_out;

    // 4096 output rows, 4 waves per block -> 1024 blocks
    const int blocks = (out_size / 32) / 4;
    fused_pool_lse_relu<<<blocks, 256, 0, stream>>>(x, bias, out);
}

// Round 10
// 43.214 us; speedup vs baseline: 1.0492x; 1.0474x over previous
//
#include <hip/hip_runtime.h>

// Fused: 2x2x2 max-pool (stride 2) + per-channel bias + logsumexp over C=64 + ReLU.
// x = const float* [4,64,64,64,64] (harness upcasts fp16->f32), bias = const float* [64],
// out = float* [4,1,32,32,32]  (dtype forensics: R1..R3 error magnitudes).
//
// FINAL (= R4, the ladder's best). Probes R5-R9 tested float4 width (45.4/45.3),
// 2x occupancy (43.4 — tie), and nontemporal loads (45.3 — forfeits cross-replay
// L3 hits). Plateau: 43.4 us = 6.20 TB/s = 98.5% of the measured copy ceiling
// (6.29 TB/s). Compulsory traffic 268.96 MB, read exactly once, 0 reducible
// bytes -> memory roofline reached.
//
// Decomposition: each output voxel owned by a lane PAIR (i, i+32): half 0 does
// channels 0..31, half 1 channels 32..63; merge (m,s) via one __shfl_xor(.,32).
// 4096 waves = 16/CU. float2 loads (8 B/lane, 256 B/segment), fully coalesced.

__global__ __launch_bounds__(256) void fused_pool_lse_relu(
    const float* __restrict__ x, const float* __restrict__ bias,
    float* __restrict__ out)
{
    __shared__ float s_bias[64];
    if (threadIdx.x < 64) s_bias[threadIdx.x] = bias[threadIdx.x];
    __syncthreads();

    const int lane  = threadIdx.x & 63;
    const int wave  = threadIdx.x >> 6;
    const int chalf = lane >> 5;                        // 0: c=0..31, 1: c=32..63
    const int o     = blockIdx.x * 128 + wave * 32 + (lane & 31);

    const int wp = o & 31;          // output w'
    const int hp = (o >> 5) & 31;   // output h'
    const int dp = (o >> 10) & 31;  // output d'
    const int n  = o >> 15;         // batch

    // element strides (f32): w:1, h:64, d:4096, c:262144, n:64*262144
    const size_t CS = 262144;
    const float* base = x
        + (size_t)n * (64 * CS)
        + (size_t)(chalf * 32) * CS
        + (size_t)dp * 8192        // 2*dp*4096
        + (size_t)hp * 128         // 2*hp*64
        + (size_t)wp * 2;

    float vals[32];
#pragma unroll
    for (int cc = 0; cc < 32; ++cc) {
        const float* p = base + (size_t)cc * CS;
        const float2 a = *(const float2*)(p);          // d0,h0 (w0,w1)
        const float2 b = *(const float2*)(p + 64);     // d0,h1
        const float2 c = *(const float2*)(p + 4096);   // d1,h0
        const float2 d = *(const float2*)(p + 4160);   // d1,h1
        const float v = fmaxf(fmaxf(fmaxf(a.x, a.y), fmaxf(b.x, b.y)),
                              fmaxf(fmaxf(c.x, c.y), fmaxf(d.x, d.y)));
        vals[cc] = v + s_bias[chalf * 32 + cc];
    }

    // two-pass logsumexp over this lane's 32 channels (all indices static)
    float m = vals[0];
#pragma unroll
    for (int cc = 1; cc < 32; ++cc) m = fmaxf(m, vals[cc]);
    float s = 0.0f;
#pragma unroll
    for (int cc = 0; cc < 32; ++cc) s += __expf(vals[cc] - m);

    // merge the two channel-halves across the lane pair
    const float m2 = __shfl_xor(m, 32);
    const float s2 = __shfl_xor(s, 32);
    const float M  = fmaxf(m, m2);
    const float st = s * __expf(m - M) + s2 * __expf(m2 - M);
    const float r  = fmaxf(M + __logf(st), 0.0f);   // ReLU

    if (chalf == 0) out[o] = r;
}

extern "C" void kernel_launch(void* const* d_in, const int* in_sizes, int n_in,
                              void* d_out, int out_size, void* d_ws, size_t ws_size,
                              hipStream_t stream)
{
    const float* x    = (const float*)d_in[0];
    const float* bias = (const float*)d_in[1];
    float* out = (float*)d_out;

    // out_size = 4*32*32*32 = 131072; each block covers 128 outputs
    const int blocks = out_size / 128;   // 1024
    fused_pool_lse_relu<<<blocks, 256, 0, stream>>>(x, bias, out);
}